// Round 4
// baseline (5782.554 us; speedup 1.0000x reference)
//
#include <hip/hip_runtime.h>
#include <stdint.h>

#define NR 100000L   // N rows
#define NC 64        // split-K chunks for utx (VALU version)
#define CH 1568L     // n per chunk (196*8); 64*1568 = 100352 >= NR
#define LSTR 72      // padded LDS row stride (elements) for [*][64] bf16 tiles

typedef __attribute__((ext_vector_type(8))) short s16x8;
typedef __attribute__((ext_vector_type(4))) short s16x4;
typedef __attribute__((ext_vector_type(4))) float f32x4;

__device__ __forceinline__ unsigned short f2bf(float f) {
  union { float f; unsigned u; } v; v.f = f;
  unsigned r = v.u + 0x7FFFu + ((v.u >> 16) & 1u);   // RNE
  return (unsigned short)(r >> 16);
}
__device__ __forceinline__ float bf2f(unsigned short s) {
  union { unsigned u; float f; } v; v.u = ((unsigned)s) << 16;
  return v.f;
}
__device__ __forceinline__ f32x4 MF(s16x8 a, s16x8 b, f32x4 c) {
  return __builtin_amdgcn_mfma_f32_16x16x32_bf16(a, b, c, 0, 0, 0);
}

// ---------- LDS staging for the MFMA encoder GEMMs ----------
template<int ROWS>
__device__ __forceinline__ void stage_rows(unsigned short* lds, const unsigned short* src,
    long pitch, long r0, long rlim, long k0, long klim, int tid) {
  const int f8 = tid & 7;
#pragma unroll
  for (int it = 0; it < ROWS / 32; ++it) {
    const int row = (tid >> 3) + it * 32;
    const long gr = r0 + row;
    const long gk = k0 + f8 * 8;
    s16x8 v = {};
    if (gr < rlim && gk < klim)
      v = *(const s16x8*)(src + gr * pitch + gk);
    *(s16x8*)(lds + row * LSTR + f8 * 8) = v;
  }
}

template<int ROWS>
__device__ __forceinline__ void stage_rows_f32(unsigned short* lds, const float* src,
    long pitch, long r0, long rlim, long k0, long klim, int tid) {
  const int f4 = tid & 15;
#pragma unroll
  for (int it = 0; it < ROWS / 16; ++it) {
    const int row = (tid >> 4) + it * 16;
    const long gr = r0 + row;
    const long gk = k0 + f4 * 4;
    f32x4 v = {};
    if (gr < rlim && gk < klim)
      v = *(const f32x4*)(src + gr * pitch + gk);
    s16x4 o;
    o[0] = (short)f2bf(v[0]); o[1] = (short)f2bf(v[1]);
    o[2] = (short)f2bf(v[2]); o[3] = (short)f2bf(v[3]);
    *(s16x4*)(lds + row * LSTR + f4 * 4) = o;
  }
}

__device__ __forceinline__ s16x8 fragA(const unsigned short* lds, int row, int kk, int lane) {
  return *(const s16x8*)(lds + row * LSTR + kk * 32 + ((lane >> 4) << 3));
}

// ---------- prep ----------
__global__ void k_prep(const float* __restrict__ e0, const float* __restrict__ e1,
    const float* __restrict__ fe_w1, const float* __restrict__ fe_w2,
    const float* __restrict__ eig_w, const float* __restrict__ eig_b,
    const float* __restrict__ lw, const float* __restrict__ fW,
    unsigned short* __restrict__ W1T, unsigned short* __restrict__ W2T,
    float* __restrict__ eig, float* __restrict__ coef) {
  long id = (long)blockIdx.x * 256 + threadIdx.x;
  if (id < 65536) {                       // W1T[j][k]
    int j = (int)(id >> 9), k = (int)(id & 511);
    W1T[id] = (k < 500) ? f2bf(fe_w1[(long)k * 128 + j]) : (unsigned short)0;
  } else if (id < 65536 + 16384) {        // W2T[j][k]
    long q = id - 65536; int j = (int)(q >> 7), k = (int)(q & 127);
    W2T[q] = f2bf(fe_w2[(long)k * 128 + j]);
  } else if (id < 65536 + 16384 + 1024) { // eig[b][m]
    long q = id - 65536 - 16384; int b = (int)(q >> 9), m = (int)(q & 511);
    const float* e = b ? e1 : e0;
    float s = eig_b[0] + eig_w[0];
    float pe = 3.14159265358979323846f * e[m];
    for (int f = 1; f <= 128; ++f) s += cosf(pe * (float)f) * eig_w[f];
    eig[q] = s;
  } else if (id < 65536 + 16384 + 1024 + 256) { // coef[L][{c0,c1}][j]
    long q = id - 65536 - 16384 - 1024; int L = (int)(q >> 7), j = (int)(q & 127);
    float tail = 0.f;
    for (int k = 1; k <= 10; ++k) tail += fW[k];
    float w0 = lw[L * 256 + j], w1 = lw[L * 256 + 128 + j];
    coef[L * 256 + j] = w0 + fW[0] * w1;
    coef[L * 256 + 128 + j] = tail * w1;
  }
}

// ---------- GEMM1: t[n][j] = relu(x @ W1 + b1) ----------
__global__ __launch_bounds__(256) void k_gemm1(const float* __restrict__ x,
    const unsigned short* __restrict__ W1T, const float* __restrict__ b1,
    unsigned short* __restrict__ t) {
  __shared__ __align__(16) unsigned short Al[64 * LSTR];
  __shared__ __align__(16) unsigned short Bl[128 * LSTR];
  const int tid = threadIdx.x, lane = tid & 63, w = tid >> 6;
  const long n0 = (long)blockIdx.x * 64;
  f32x4 acc[8] = {};
  for (int kt = 0; kt < 8; ++kt) {
    stage_rows_f32<64>(Al, x, 500, n0, NR, kt * 64L, 500, tid);
    stage_rows<128>(Bl, W1T, 512, 0, 1L << 40, kt * 64L, 512, tid);
    __syncthreads();
#pragma unroll
    for (int kk = 0; kk < 2; ++kk) {
      s16x8 af = fragA(Al, (w << 4) + (lane & 15), kk, lane);
#pragma unroll
      for (int ct = 0; ct < 8; ++ct) {
        s16x8 bfr = fragA(Bl, (ct << 4) + (lane & 15), kk, lane);
        acc[ct] = MF(af, bfr, acc[ct]);
      }
    }
    __syncthreads();
  }
  const int cl = lane & 15, g = lane >> 4;
#pragma unroll
  for (int ct = 0; ct < 8; ++ct) {
    int j = (ct << 4) + cl;
    float bias = b1[j];
#pragma unroll
    for (int r = 0; r < 4; ++r) {
      long n = n0 + (w << 4) + (g << 2) + r;
      if (n < NR) {
        float v = acc[ct][r] + bias;
        t[n * 128 + j] = f2bf(v > 0.f ? v : 0.f);
      }
    }
  }
}

// ---------- GEMM2: hT[j][n] = (t @ W2 + b2)^T ----------
__global__ __launch_bounds__(256) void k_gemm2(const unsigned short* __restrict__ W2T,
    const unsigned short* __restrict__ t, const float* __restrict__ b2,
    unsigned short* __restrict__ hT) {
  __shared__ __align__(16) unsigned short Al[128 * LSTR];
  __shared__ __align__(16) unsigned short Bl[64 * LSTR];
  const int tid = threadIdx.x, lane = tid & 63, w = tid >> 6;
  const long n0 = (long)blockIdx.x * 64;
  f32x4 acc[8] = {};
  for (int kt = 0; kt < 2; ++kt) {
    stage_rows<128>(Al, W2T, 128, 0, 1L << 40, kt * 64L, 128, tid);
    stage_rows<64>(Bl, t, 128, n0, NR, kt * 64L, 128, tid);
    __syncthreads();
#pragma unroll
    for (int kk = 0; kk < 2; ++kk) {
      s16x8 bfr = fragA(Bl, (w << 4) + (lane & 15), kk, lane);
#pragma unroll
      for (int rt = 0; rt < 8; ++rt) {
        s16x8 af = fragA(Al, (rt << 4) + (lane & 15), kk, lane);
        acc[rt] = MF(af, bfr, acc[rt]);
      }
    }
    __syncthreads();
  }
  const int cl = lane & 15, g = lane >> 4;
  long n = n0 + (w << 4) + cl;
  if (n < NR) {
#pragma unroll
    for (int rt = 0; rt < 8; ++rt)
#pragma unroll
      for (int r = 0; r < 4; ++r) {
        int j = (rt << 4) + (g << 2) + r;
        hT[(long)j * NR + n] = f2bf(acc[rt][r] + b2[j]);
      }
  }
}

// ---------- utx, VALU f32: P[c][m][j] partial of u^T h over n-chunk ----------
__global__ __launch_bounds__(256) void k_utxV(const unsigned short* __restrict__ hT,
    const float* __restrict__ u, float* __restrict__ P) {
  __shared__ float us[8][64];
  __shared__ float hs[8][128];
  const int tid = threadIdx.x;
  const int mt = blockIdx.x & 7, c = blockIdx.x >> 3;
  const long m0 = (long)mt * 64, nb = (long)c * CH;
  const int lane = tid & 63, wv = tid >> 6;   // thread owns m=m0+lane, j = wv*4 + q*16 + e
  f32x4 acc[8] = {};
  for (int s = 0; s < 196; ++s) {
    const long n0 = nb + s * 8;
    __syncthreads();
    {
      int idx = tid;
#pragma unroll
      for (int rep = 0; rep < 2; ++rep, idx += 256) {
        int i = idx >> 6, mm = idx & 63;
        long n = n0 + i;
        us[i][mm] = (n < NR) ? u[n * 512 + m0 + mm] : 0.f;
      }
    }
    {
      int idx = tid;
#pragma unroll
      for (int rep = 0; rep < 4; ++rep, idx += 256) {
        int i = idx & 7, jj = idx >> 3;      // i fast -> 16B-contiguous global reads
        long n = n0 + i;
        hs[i][jj] = (n < NR) ? bf2f(hT[(long)jj * NR + n]) : 0.f;
      }
    }
    __syncthreads();
#pragma unroll
    for (int i = 0; i < 8; ++i) {
      float uv = us[i][lane];
#pragma unroll
      for (int q = 0; q < 8; ++q) {
        f32x4 hv = *(const f32x4*)&hs[i][wv * 4 + q * 16];
        acc[q][0] += uv * hv[0];
        acc[q][1] += uv * hv[1];
        acc[q][2] += uv * hv[2];
        acc[q][3] += uv * hv[3];
      }
    }
  }
  float* Pc = P + (long)c * 65536 + (m0 + lane) * 128 + wv * 4;
#pragma unroll
  for (int q = 0; q < 8; ++q)
    *(f32x4*)(Pc + q * 16) = acc[q];
}

// ---------- reduce split-K partials, apply eig -> s32[m][j] (f32) ----------
__global__ void k_reduceV(const float* __restrict__ P, const float* __restrict__ eig,
                          float* __restrict__ s32) {
  const int t4 = blockIdx.x * 256 + threadIdx.x;   // 16384 threads x f32x4
  f32x4 s = {};
  const float* p = P + (long)t4 * 4;
  for (int c = 0; c < NC; ++c) {
    f32x4 v = *(const f32x4*)(p + (long)c * 65536);
    s[0] += v[0]; s[1] += v[1]; s[2] += v[2]; s[3] += v[3];
  }
  const int m = t4 >> 5;                           // idx = t4*4; m = idx>>7
  const float ev = eig[m];
  s[0] *= ev; s[1] *= ev; s[2] *= ev; s[3] *= ev;
  *(f32x4*)(s32 + (long)t4 * 4) = s;
}

// ---------- r-GEMM VALU f32 + fused layer update/LN/ReLU ----------
__global__ __launch_bounds__(256) void k_rgemmV(const float* __restrict__ s32,
    const float* __restrict__ u, const unsigned short* __restrict__ hin,
    unsigned short* __restrict__ hout, const float* __restrict__ c0,
    const float* __restrict__ c1, const float* __restrict__ gam,
    const float* __restrict__ bet) {
  __shared__ float us[64][65];       // padded
  __shared__ float ss[64][128];
  const int tid = threadIdx.x;
  const long n0 = (long)blockIdx.x * 64;
  const int lane = tid & 63, wv = tid >> 6;
  const int nl = wv * 16 + (lane & 15);   // local n row
  const int g = lane >> 4;                // j = g*4 + q*16 + e
  const long n = n0 + nl;
  f32x4 acc[8] = {};
  for (int mt = 0; mt < 8; ++mt) {
    __syncthreads();
    {
      int idx = tid;
#pragma unroll
      for (int rep = 0; rep < 16; ++rep, idx += 256) {
        int r = idx >> 6, mm = idx & 63;
        long gn = n0 + r;
        us[r][mm] = (gn < NR) ? u[gn * 512 + mt * 64 + mm] : 0.f;
      }
    }
    {
      int idx = tid;
#pragma unroll
      for (int rep = 0; rep < 32; ++rep, idx += 256) {
        int ml = idx >> 7, jj = idx & 127;
        ss[ml][jj] = s32[(long)(mt * 64 + ml) * 128 + jj];
      }
    }
    __syncthreads();
#pragma unroll 8
    for (int mm = 0; mm < 64; ++mm) {
      float uv = us[nl][mm];
#pragma unroll
      for (int q = 0; q < 8; ++q) {
        f32x4 sv = *(const f32x4*)&ss[mm][g * 4 + q * 16];
        acc[q][0] += uv * sv[0];
        acc[q][1] += uv * sv[1];
        acc[q][2] += uv * sv[2];
        acc[q][3] += uv * sv[3];
      }
    }
  }
  // fused: p = h*c0 + c1*r; LN over j; relu
  const bool valid = n < NR;
  float pre[8][4];
  float sum = 0.f, ssq = 0.f;
#pragma unroll
  for (int q = 0; q < 8; ++q)
#pragma unroll
    for (int e = 0; e < 4; ++e) {
      int j = g * 4 + q * 16 + e;
      float hp = valid ? bf2f(hin[(long)j * NR + n]) : 0.f;
      float pv = hp * c0[j] + c1[j] * acc[q][e];
      pre[q][e] = pv;
      sum += pv; ssq += pv * pv;
    }
  sum += __shfl_xor(sum, 16, 64); sum += __shfl_xor(sum, 32, 64);
  ssq += __shfl_xor(ssq, 16, 64); ssq += __shfl_xor(ssq, 32, 64);
  const float mu = sum * (1.f / 128.f);
  const float var = ssq * (1.f / 128.f) - mu * mu;
  const float rs = rsqrtf(var + 1e-5f);
  if (valid) {
#pragma unroll
    for (int q = 0; q < 8; ++q)
#pragma unroll
      for (int e = 0; e < 4; ++e) {
        int j = g * 4 + q * 16 + e;
        float o = (pre[q][e] - mu) * rs * gam[j] + bet[j];
        hout[(long)j * NR + n] = f2bf(o > 0.f ? o : 0.f);
      }
  }
}

// ---------- final: attention mix + 128->40 GEMV + log_softmax ----------
__global__ __launch_bounds__(256) void k_final(const unsigned short* __restrict__ R0,
    const unsigned short* __restrict__ R1, const unsigned short* __restrict__ R2,
    const float* __restrict__ att0, const float* __restrict__ att1,
    const float* __restrict__ att2, const float* __restrict__ av,
    const float* __restrict__ W, const float* __restrict__ bias,
    float* __restrict__ out) {
  __shared__ __align__(16) float Wl[128 * 40];
  __shared__ float Av[3][128];
  __shared__ float zb[256 * 41];
  const int tid = threadIdx.x;
  for (int i = tid; i < 5120; i += 256) Wl[i] = W[i];
  if (tid < 128) { Av[0][tid] = att0[tid]; Av[1][tid] = att1[tid]; Av[2][tid] = att2[tid]; }
  __syncthreads();
  const long n0 = (long)blockIdx.x * 256;
  const long n = n0 + tid;
  const long nn = n < NR ? n : NR - 1;
  float a0 = 0.f, a1 = 0.f, a2 = 0.f;
  for (int j = 0; j < 128; ++j) {
    a0 += bf2f(R0[(long)j * NR + nn]) * Av[0][j];
    a1 += bf2f(R1[(long)j * NR + nn]) * Av[1][j];
    a2 += bf2f(R2[(long)j * NR + nn]) * Av[2][j];
  }
  const float s0 = 1.f / (1.f + expf(-a0));
  const float s1 = 1.f / (1.f + expf(-a1));
  const float s2 = 1.f / (1.f + expf(-a2));
  const float l0 = s0 * av[0] + s1 * av[3] + s2 * av[6];
  const float l1 = s0 * av[1] + s1 * av[4] + s2 * av[7];
  const float l2 = s0 * av[2] + s1 * av[5] + s2 * av[8];
  const float mx = fmaxf(l0, fmaxf(l1, l2));
  const float e0v = expf(l0 - mx), e1v = expf(l1 - mx), e2v = expf(l2 - mx);
  const float inv = 1.f / (e0v + e1v + e2v);
  const float w0 = e0v * inv, w1 = e1v * inv, w2 = e2v * inv;
  float z[40];
#pragma unroll
  for (int c = 0; c < 40; ++c) z[c] = bias[c];
  for (int j = 0; j < 128; ++j) {
    const float h = w0 * bf2f(R0[(long)j * NR + nn]) + w1 * bf2f(R1[(long)j * NR + nn])
                  + w2 * bf2f(R2[(long)j * NR + nn]);
#pragma unroll
    for (int c4 = 0; c4 < 10; ++c4) {
      f32x4 wv = *(const f32x4*)(&Wl[j * 40 + c4 * 4]);
      z[c4 * 4 + 0] += h * wv[0];
      z[c4 * 4 + 1] += h * wv[1];
      z[c4 * 4 + 2] += h * wv[2];
      z[c4 * 4 + 3] += h * wv[3];
    }
  }
  float mz = z[0];
#pragma unroll
  for (int c = 1; c < 40; ++c) mz = fmaxf(mz, z[c]);
  float se = 0.f;
#pragma unroll
  for (int c = 0; c < 40; ++c) se += expf(z[c] - mz);
  const float ls = logf(se);
#pragma unroll
  for (int c = 0; c < 40; ++c) zb[tid * 41 + c] = z[c] - mz - ls;
  __syncthreads();
  long rows = NR - n0; if (rows > 256) rows = 256;
  const long cnt = rows * 40;
  for (long i = tid; i < cnt; i += 256)
    out[n0 * 40 + i] = zb[(i / 40) * 41 + (i % 40)];
}

extern "C" void kernel_launch(void* const* d_in, const int* in_sizes, int n_in,
                              void* d_out, int out_size, void* d_ws, size_t ws_size,
                              hipStream_t stream) {
  const float* x      = (const float*)d_in[0];
  const float* e0     = (const float*)d_in[1];
  const float* e1     = (const float*)d_in[2];
  const float* u0     = (const float*)d_in[3];
  const float* u1     = (const float*)d_in[4];
  const float* fe_w1  = (const float*)d_in[5];
  const float* fe_b1  = (const float*)d_in[6];
  const float* fe_w2  = (const float*)d_in[7];
  const float* fe_b2  = (const float*)d_in[8];
  const float* eig_w  = (const float*)d_in[9];
  const float* eig_bi = (const float*)d_in[10];
  const float* lw     = (const float*)d_in[11];
  const float* ln_g   = (const float*)d_in[12];
  const float* ln_b   = (const float*)d_in[13];
  const float* fW     = (const float*)d_in[14];
  const float* att0   = (const float*)d_in[15];
  const float* att1   = (const float*)d_in[16];
  const float* att2   = (const float*)d_in[17];
  const float* attv   = (const float*)d_in[18];
  const float* lin3w  = (const float*)d_in[19];
  const float* lin3b  = (const float*)d_in[20];
  float* out = (float*)d_out;

  const size_t SZ_H = (size_t)NR * 128 * 2;        // 25,600,000
  const size_t SZ_P = (size_t)NC * 65536 * 4;      // 16,777,216

  char* p = (char*)d_ws;
  unsigned short* TT  = (unsigned short*)p; p += SZ_H;
  unsigned short* R0T = (unsigned short*)p; p += SZ_H;
  unsigned short* R1T = (unsigned short*)p; p += SZ_H;
  unsigned short* R2T = (unsigned short*)p; p += SZ_H;
  float* P            = (float*)p;          p += SZ_P;
  float* s32          = (float*)p;          p += 65536 * 4;
  unsigned short* W1T = (unsigned short*)p; p += 131072;
  unsigned short* W2T = (unsigned short*)p; p += 32768;
  float* eig          = (float*)p;          p += 4096;
  float* coef         = (float*)p;          p += 2048;

  k_prep<<<325, 256, 0, stream>>>(e0, e1, fe_w1, fe_w2, eig_w, eig_bi, lw, fW,
                                  W1T, W2T, eig, coef);
  const int GB = (int)((NR + 63) / 64);   // 1563
  k_gemm1<<<GB, 256, 0, stream>>>(x, W1T, fe_b1, TT);
  k_gemm2<<<GB, 256, 0, stream>>>(W2T, TT, fe_b2, R0T);

  for (int b = 0; b < 2; ++b) {
    const float* u = b ? u1 : u0;
    // CRITICAL: h carries across branches in the reference — branch 1 starts
    // from branch 0's final h (R1T), NOT from the encoder output.
    const unsigned short* hin = (b == 0) ? R0T : R1T;
    for (int L = 0; L < 2; ++L) {
      unsigned short* hout = (L == 0) ? TT : (b ? R2T : R1T);
      k_utxV<<<8 * NC, 256, 0, stream>>>(hin, u, P);
      k_reduceV<<<64, 256, 0, stream>>>(P, eig + b * 512, s32);
      k_rgemmV<<<GB, 256, 0, stream>>>(s32, u, hin, hout,
          coef + L * 256, coef + L * 256 + 128, ln_g + L * 128, ln_b + L * 128);
      hin = hout;
    }
  }
  k_final<<<(int)((NR + 255) / 256), 256, 0, stream>>>(R0T, R1T, R2T,
      att0, att1, att2, attv, lin3w, lin3b, out);
}

// Round 5
// 1304.551 us; speedup vs baseline: 4.4326x; 4.4326x over previous
//
#include <hip/hip_runtime.h>
#include <stdint.h>

#define NR 100000L   // N rows
#define KC 96        // split-K chunks for utx
#define CHN 1088L    // n-chunk per utx block = 17*64
#define LSTR 72      // padded LDS row stride (elements) for [*][64] bf16 tiles

typedef __attribute__((ext_vector_type(8))) short s16x8;
typedef __attribute__((ext_vector_type(4))) short s16x4;
typedef __attribute__((ext_vector_type(4))) float f32x4;

__device__ __forceinline__ unsigned short f2bf(float f) {
  union { float f; unsigned u; } v; v.f = f;
  unsigned r = v.u + 0x7FFFu + ((v.u >> 16) & 1u);   // RNE
  return (unsigned short)(r >> 16);
}
__device__ __forceinline__ float bf2f(unsigned short s) {
  union { unsigned u; float f; } v; v.u = ((unsigned)s) << 16;
  return v.f;
}
__device__ __forceinline__ f32x4 MF(s16x8 a, s16x8 b, f32x4 c) {
  return __builtin_amdgcn_mfma_f32_16x16x32_bf16(a, b, c, 0, 0, 0);
}

// ---------- LDS staging: tiles [ROWS][64] bf16 at padded stride LSTR=72 ----------
template<int ROWS>
__device__ __forceinline__ void stage_rows(unsigned short* lds, const unsigned short* src,
    long pitch, long r0, long rlim, long k0, long klim, int tid) {
  const int f8 = tid & 7;
#pragma unroll
  for (int it = 0; it < ROWS / 32; ++it) {
    const int row = (tid >> 3) + it * 32;
    const long gr = r0 + row;
    const long gk = k0 + f8 * 8;
    s16x8 v = {};
    if (gr < rlim && gk < klim)
      v = *(const s16x8*)(src + gr * pitch + gk);
    *(s16x8*)(lds + row * LSTR + f8 * 8) = v;
  }
}

template<int ROWS>
__device__ __forceinline__ void stage_rows_f32(unsigned short* lds, const float* src,
    long pitch, long r0, long rlim, long k0, long klim, int tid) {
  const int f4 = tid & 15;
#pragma unroll
  for (int it = 0; it < ROWS / 16; ++it) {
    const int row = (tid >> 4) + it * 16;
    const long gr = r0 + row;
    const long gk = k0 + f4 * 4;
    f32x4 v = {};
    if (gr < rlim && gk < klim)
      v = *(const f32x4*)(src + gr * pitch + gk);
    s16x4 o;
    o[0] = (short)f2bf(v[0]); o[1] = (short)f2bf(v[1]);
    o[2] = (short)f2bf(v[2]); o[3] = (short)f2bf(v[3]);
    *(s16x4*)(lds + row * LSTR + f4 * 4) = o;
  }
}

// Transposed stager for utx B-operand: Btr[m_local][n_local] = u[n0+nl][m0+mm].
__device__ __forceinline__ void stage_utr_f32(unsigned short* lds, const float* u,
    long n0, long m0, int tid) {
  const int mm = tid & 63;
  const int base = tid >> 6;
#pragma unroll
  for (int it = 0; it < 16; ++it) {
    const int nl = base + it * 4;
    const long n = n0 + nl;
    unsigned short v = 0;
    if (n < NR) v = f2bf(u[n * 512 + m0 + mm]);
    lds[mm * LSTR + nl] = v;
  }
}

// Fragment reader: lane l holds row (passed), k = kk*32 + (l>>4)*8 .. +8 contiguous.
__device__ __forceinline__ s16x8 fragA(const unsigned short* lds, int row, int kk, int lane) {
  return *(const s16x8*)(lds + row * LSTR + kk * 32 + ((lane >> 4) << 3));
}

// ---------- prep ----------
__global__ void k_prep(const float* __restrict__ e0, const float* __restrict__ e1,
    const float* __restrict__ fe_w1, const float* __restrict__ fe_w2,
    const float* __restrict__ eig_w, const float* __restrict__ eig_b,
    const float* __restrict__ lw, const float* __restrict__ fW,
    unsigned short* __restrict__ W1T, unsigned short* __restrict__ W2T,
    float* __restrict__ eig, float* __restrict__ coef) {
  long id = (long)blockIdx.x * 256 + threadIdx.x;
  if (id < 65536) {                       // W1T[j][k]
    int j = (int)(id >> 9), k = (int)(id & 511);
    W1T[id] = (k < 500) ? f2bf(fe_w1[(long)k * 128 + j]) : (unsigned short)0;
  } else if (id < 65536 + 16384) {        // W2T[j][k]
    long q = id - 65536; int j = (int)(q >> 7), k = (int)(q & 127);
    W2T[q] = f2bf(fe_w2[(long)k * 128 + j]);
  } else if (id < 65536 + 16384 + 1024) { // eig[b][m]
    long q = id - 65536 - 16384; int b = (int)(q >> 9), m = (int)(q & 511);
    const float* e = b ? e1 : e0;
    float s = eig_b[0] + eig_w[0];
    float pe = 3.14159265358979323846f * e[m];
    for (int f = 1; f <= 128; ++f) s += cosf(pe * (float)f) * eig_w[f];
    eig[q] = s;
  } else if (id < 65536 + 16384 + 1024 + 256) { // coef[L][{c0,c1}][j]
    long q = id - 65536 - 16384 - 1024; int L = (int)(q >> 7), j = (int)(q & 127);
    float tail = 0.f;
    for (int k = 1; k <= 10; ++k) tail += fW[k];
    float w0 = lw[L * 256 + j], w1 = lw[L * 256 + 128 + j];
    coef[L * 256 + j] = w0 + fW[0] * w1;
    coef[L * 256 + 128 + j] = tail * w1;
  }
}

// ---------- GEMM1: t[n][j] = relu(x @ W1 + b1). D rows = n (64), cols = j (128).
__global__ __launch_bounds__(256) void k_gemm1(const float* __restrict__ x,
    const unsigned short* __restrict__ W1T, const float* __restrict__ b1,
    unsigned short* __restrict__ t) {
  __shared__ __align__(16) unsigned short Al[64 * LSTR];
  __shared__ __align__(16) unsigned short Bl[128 * LSTR];
  const int tid = threadIdx.x, lane = tid & 63, w = tid >> 6;
  const long n0 = (long)blockIdx.x * 64;
  f32x4 acc[8] = {};
  for (int kt = 0; kt < 8; ++kt) {
    stage_rows_f32<64>(Al, x, 500, n0, NR, kt * 64L, 500, tid);
    stage_rows<128>(Bl, W1T, 512, 0, 1L << 40, kt * 64L, 512, tid);
    __syncthreads();
#pragma unroll
    for (int kk = 0; kk < 2; ++kk) {
      s16x8 af = fragA(Al, (w << 4) + (lane & 15), kk, lane);
#pragma unroll
      for (int ct = 0; ct < 8; ++ct) {
        s16x8 bfr = fragA(Bl, (ct << 4) + (lane & 15), kk, lane);
        acc[ct] = MF(af, bfr, acc[ct]);
      }
    }
    __syncthreads();
  }
  const int cl = lane & 15, g = lane >> 4;
#pragma unroll
  for (int ct = 0; ct < 8; ++ct) {
    int j = (ct << 4) + cl;
    float bias = b1[j];
#pragma unroll
    for (int r = 0; r < 4; ++r) {
      long n = n0 + (w << 4) + (g << 2) + r;
      if (n < NR) {
        float v = acc[ct][r] + bias;
        t[n * 128 + j] = f2bf(v > 0.f ? v : 0.f);
      }
    }
  }
}

// ---------- GEMM2: hT[j][n] = (t @ W2 + b2)^T. D rows = j (128), cols = n (64).
__global__ __launch_bounds__(256) void k_gemm2(const unsigned short* __restrict__ W2T,
    const unsigned short* __restrict__ t, const float* __restrict__ b2,
    unsigned short* __restrict__ hT) {
  __shared__ __align__(16) unsigned short Al[128 * LSTR];
  __shared__ __align__(16) unsigned short Bl[64 * LSTR];
  const int tid = threadIdx.x, lane = tid & 63, w = tid >> 6;
  const long n0 = (long)blockIdx.x * 64;
  f32x4 acc[8] = {};
  for (int kt = 0; kt < 2; ++kt) {
    stage_rows<128>(Al, W2T, 128, 0, 1L << 40, kt * 64L, 128, tid);
    stage_rows<64>(Bl, t, 128, n0, NR, kt * 64L, 128, tid);
    __syncthreads();
#pragma unroll
    for (int kk = 0; kk < 2; ++kk) {
      s16x8 bfr = fragA(Bl, (w << 4) + (lane & 15), kk, lane);
#pragma unroll
      for (int rt = 0; rt < 8; ++rt) {
        s16x8 af = fragA(Al, (rt << 4) + (lane & 15), kk, lane);
        acc[rt] = MF(af, bfr, acc[rt]);
      }
    }
    __syncthreads();
  }
  const int cl = lane & 15, g = lane >> 4;
  long n = n0 + (w << 4) + cl;
  if (n < NR) {
#pragma unroll
    for (int rt = 0; rt < 8; ++rt)
#pragma unroll
      for (int r = 0; r < 4; ++r) {
        int j = (rt << 4) + (g << 2) + r;
        hT[(long)j * NR + n] = f2bf(acc[rt][r] + b2[j]);
      }
  }
}

// ---------- utx (split-K, MFMA): P[c][j][m] partial of (u^T h)^T over n-chunk ----------
__global__ __launch_bounds__(256) void k_utx(const unsigned short* __restrict__ hT,
    const float* __restrict__ u, float* __restrict__ P) {
  __shared__ __align__(16) unsigned short Al[128 * LSTR];
  __shared__ __align__(16) unsigned short Bl[64 * LSTR];
  const int tid = threadIdx.x, lane = tid & 63, w = tid >> 6;
  const int mt = blockIdx.x & 7, c = blockIdx.x >> 3;
  const long m0 = (long)mt * 64, nb = (long)c * CHN;
  f32x4 acc[8] = {};
  for (int kt = 0; kt < 17; ++kt) {
    const long n0 = nb + kt * 64;
    stage_rows<128>(Al, hT, NR, 0, 1L << 40, n0, NR, tid);
    stage_utr_f32(Bl, u, n0, m0, tid);
    __syncthreads();
#pragma unroll
    for (int kk = 0; kk < 2; ++kk) {
      s16x8 bfr = fragA(Bl, (w << 4) + (lane & 15), kk, lane);
#pragma unroll
      for (int rt = 0; rt < 8; ++rt) {
        s16x8 af = fragA(Al, (rt << 4) + (lane & 15), kk, lane);
        acc[rt] = MF(af, bfr, acc[rt]);
      }
    }
    __syncthreads();
  }
  const int cl = lane & 15, g = lane >> 4;
  const long m = m0 + (w << 4) + cl;
  float* Pc = P + (long)c * 65536;
#pragma unroll
  for (int rt = 0; rt < 8; ++rt)
#pragma unroll
    for (int r = 0; r < 4; ++r) {
      int j = (rt << 4) + (g << 2) + r;
      Pc[(long)j * 512 + m] = acc[rt][r];
    }
}

// ---------- reduce split-K partials, apply eig scaling -> sT[j][m] bf16 ----------
__global__ void k_reduce(const float* __restrict__ P, const float* __restrict__ eig,
                         unsigned short* __restrict__ sT) {
  const int idx = blockIdx.x * 256 + threadIdx.x;   // 65536
  const int m = idx & 511;
  float s = 0.f;
#pragma unroll 4
  for (int c = 0; c < KC; ++c) s += P[(long)c * 65536 + idx];
  sT[idx] = f2bf(s * eig[m]);
}

// ---------- r-GEMM (MFMA) + fused layer update/LN/ReLU ----------
__global__ __launch_bounds__(256) void k_rgemm(const unsigned short* __restrict__ sT,
    const float* __restrict__ u, const unsigned short* __restrict__ hin,
    unsigned short* __restrict__ hout, const float* __restrict__ c0,
    const float* __restrict__ c1, const float* __restrict__ gam,
    const float* __restrict__ bet) {
  __shared__ __align__(16) unsigned short Al[128 * LSTR];
  __shared__ __align__(16) unsigned short Bl[64 * LSTR];
  const int tid = threadIdx.x, lane = tid & 63, w = tid >> 6;
  const long n0 = (long)blockIdx.x * 64;
  f32x4 acc[8] = {};
  for (int kt = 0; kt < 8; ++kt) {
    stage_rows<128>(Al, sT, 512, 0, 1L << 40, kt * 64L, 512, tid);
    stage_rows_f32<64>(Bl, u, 512, n0, NR, kt * 64L, 512, tid);
    __syncthreads();
#pragma unroll
    for (int kk = 0; kk < 2; ++kk) {
      s16x8 bfr = fragA(Bl, (w << 4) + (lane & 15), kk, lane);
#pragma unroll
      for (int rt = 0; rt < 8; ++rt) {
        s16x8 af = fragA(Al, (rt << 4) + (lane & 15), kk, lane);
        acc[rt] = MF(af, bfr, acc[rt]);
      }
    }
    __syncthreads();
  }
  // fused layer update + LayerNorm across j (rows) per column n
  const int cl = lane & 15, g = lane >> 4;
  const long n = n0 + (w << 4) + cl;
  const bool valid = n < NR;
  float pre[8][4];
  float sum = 0.f, ssq = 0.f;
#pragma unroll
  for (int rt = 0; rt < 8; ++rt)
#pragma unroll
    for (int r = 0; r < 4; ++r) {
      int j = (rt << 4) + (g << 2) + r;
      float hp = valid ? bf2f(hin[(long)j * NR + n]) : 0.f;
      float pv = hp * c0[j] + c1[j] * acc[rt][r];
      pre[rt][r] = pv;
      sum += pv; ssq += pv * pv;
    }
  sum += __shfl_xor(sum, 16, 64); sum += __shfl_xor(sum, 32, 64);
  ssq += __shfl_xor(ssq, 16, 64); ssq += __shfl_xor(ssq, 32, 64);
  const float mu = sum * (1.f / 128.f);
  const float var = ssq * (1.f / 128.f) - mu * mu;
  const float rs = rsqrtf(var + 1e-5f);
  if (valid) {
#pragma unroll
    for (int rt = 0; rt < 8; ++rt)
#pragma unroll
      for (int r = 0; r < 4; ++r) {
        int j = (rt << 4) + (g << 2) + r;
        float o = (pre[rt][r] - mu) * rs * gam[j] + bet[j];
        hout[(long)j * NR + n] = f2bf(o > 0.f ? o : 0.f);
      }
  }
}

// ---------- final: attention mix + 128->40 GEMV + log_softmax ----------
__global__ __launch_bounds__(256) void k_final(const unsigned short* __restrict__ R0,
    const unsigned short* __restrict__ R1, const unsigned short* __restrict__ R2,
    const float* __restrict__ att0, const float* __restrict__ att1,
    const float* __restrict__ att2, const float* __restrict__ av,
    const float* __restrict__ W, const float* __restrict__ bias,
    float* __restrict__ out) {
  __shared__ __align__(16) float Wl[128 * 40];
  __shared__ float Av[3][128];
  __shared__ float zb[256 * 41];
  const int tid = threadIdx.x;
  for (int i = tid; i < 5120; i += 256) Wl[i] = W[i];
  if (tid < 128) { Av[0][tid] = att0[tid]; Av[1][tid] = att1[tid]; Av[2][tid] = att2[tid]; }
  __syncthreads();
  const long n0 = (long)blockIdx.x * 256;
  const long n = n0 + tid;
  const long nn = n < NR ? n : NR - 1;
  float a0 = 0.f, a1 = 0.f, a2 = 0.f;
  for (int j = 0; j < 128; ++j) {
    a0 += bf2f(R0[(long)j * NR + nn]) * Av[0][j];
    a1 += bf2f(R1[(long)j * NR + nn]) * Av[1][j];
    a2 += bf2f(R2[(long)j * NR + nn]) * Av[2][j];
  }
  const float s0 = 1.f / (1.f + expf(-a0));
  const float s1 = 1.f / (1.f + expf(-a1));
  const float s2 = 1.f / (1.f + expf(-a2));
  const float l0 = s0 * av[0] + s1 * av[3] + s2 * av[6];
  const float l1 = s0 * av[1] + s1 * av[4] + s2 * av[7];
  const float l2 = s0 * av[2] + s1 * av[5] + s2 * av[8];
  const float mx = fmaxf(l0, fmaxf(l1, l2));
  const float e0v = expf(l0 - mx), e1v = expf(l1 - mx), e2v = expf(l2 - mx);
  const float inv = 1.f / (e0v + e1v + e2v);
  const float w0 = e0v * inv, w1 = e1v * inv, w2 = e2v * inv;
  float z[40];
#pragma unroll
  for (int c = 0; c < 40; ++c) z[c] = bias[c];
  for (int j = 0; j < 128; ++j) {
    const float h = w0 * bf2f(R0[(long)j * NR + nn]) + w1 * bf2f(R1[(long)j * NR + nn])
                  + w2 * bf2f(R2[(long)j * NR + nn]);
#pragma unroll
    for (int c4 = 0; c4 < 10; ++c4) {
      f32x4 wv = *(const f32x4*)(&Wl[j * 40 + c4 * 4]);
      z[c4 * 4 + 0] += h * wv[0];
      z[c4 * 4 + 1] += h * wv[1];
      z[c4 * 4 + 2] += h * wv[2];
      z[c4 * 4 + 3] += h * wv[3];
    }
  }
  float mz = z[0];
#pragma unroll
  for (int c = 1; c < 40; ++c) mz = fmaxf(mz, z[c]);
  float se = 0.f;
#pragma unroll
  for (int c = 0; c < 40; ++c) se += expf(z[c] - mz);
  const float ls = logf(se);
#pragma unroll
  for (int c = 0; c < 40; ++c) zb[tid * 41 + c] = z[c] - mz - ls;
  __syncthreads();
  long rows = NR - n0; if (rows > 256) rows = 256;
  const long cnt = rows * 40;
  for (long i = tid; i < cnt; i += 256)
    out[n0 * 40 + i] = zb[(i / 40) * 41 + (i % 40)];
}

extern "C" void kernel_launch(void* const* d_in, const int* in_sizes, int n_in,
                              void* d_out, int out_size, void* d_ws, size_t ws_size,
                              hipStream_t stream) {
  const float* x      = (const float*)d_in[0];
  const float* e0     = (const float*)d_in[1];
  const float* e1     = (const float*)d_in[2];
  const float* u0     = (const float*)d_in[3];
  const float* u1     = (const float*)d_in[4];
  const float* fe_w1  = (const float*)d_in[5];
  const float* fe_b1  = (const float*)d_in[6];
  const float* fe_w2  = (const float*)d_in[7];
  const float* fe_b2  = (const float*)d_in[8];
  const float* eig_w  = (const float*)d_in[9];
  const float* eig_bi = (const float*)d_in[10];
  const float* lw     = (const float*)d_in[11];
  const float* ln_g   = (const float*)d_in[12];
  const float* ln_b   = (const float*)d_in[13];
  const float* fW     = (const float*)d_in[14];
  const float* att0   = (const float*)d_in[15];
  const float* att1   = (const float*)d_in[16];
  const float* att2   = (const float*)d_in[17];
  const float* attv   = (const float*)d_in[18];
  const float* lin3w  = (const float*)d_in[19];
  const float* lin3b  = (const float*)d_in[20];
  float* out = (float*)d_out;

  const size_t SZ_H = (size_t)NR * 128 * 2;        // 25,600,000
  const size_t SZ_P = (size_t)KC * 65536 * 4;      // 25,165,824

  char* p = (char*)d_ws;
  unsigned short* TT  = (unsigned short*)p; p += SZ_H;
  unsigned short* R0T = (unsigned short*)p; p += SZ_H;
  unsigned short* R1T = (unsigned short*)p; p += SZ_H;
  unsigned short* R2T = (unsigned short*)p; p += SZ_H;
  float* P            = (float*)p;          p += SZ_P;
  unsigned short* W1T = (unsigned short*)p; p += 131072;
  unsigned short* W2T = (unsigned short*)p; p += 32768;
  unsigned short* sT  = (unsigned short*)p; p += 131072;
  float* eig          = (float*)p;          p += 4096;
  float* coef         = (float*)p;          p += 2048;

  k_prep<<<325, 256, 0, stream>>>(e0, e1, fe_w1, fe_w2, eig_w, eig_bi, lw, fW,
                                  W1T, W2T, eig, coef);
  const int GB = (int)((NR + 63) / 64);   // 1563
  k_gemm1<<<GB, 256, 0, stream>>>(x, W1T, fe_b1, TT);
  k_gemm2<<<GB, 256, 0, stream>>>(W2T, TT, fe_b2, R0T);

  for (int b = 0; b < 2; ++b) {
    const float* u = b ? u1 : u0;
    // h carries across branches: branch 1 starts from branch 0's final h (R1T).
    const unsigned short* hin = (b == 0) ? R0T : R1T;
    for (int L = 0; L < 2; ++L) {
      unsigned short* hout = (L == 0) ? TT : (b ? R2T : R1T);
      k_utx<<<8 * KC, 256, 0, stream>>>(hin, u, P);
      k_reduce<<<256, 256, 0, stream>>>(P, eig + b * 512, sT);
      k_rgemm<<<GB, 256, 0, stream>>>(sT, u, hin, hout,
          coef + L * 256, coef + L * 256 + 128, ln_g + L * 128, ln_b + L * 128);
      hin = hout;
    }
  }
  k_final<<<(int)((NR + 255) / 256), 256, 0, stream>>>(R0T, R1T, R2T,
      att0, att1, att2, attv, lin3w, lin3b, out);
}

// Round 6
// 1019.384 us; speedup vs baseline: 5.6726x; 1.2797x over previous
//
#include <hip/hip_runtime.h>
#include <stdint.h>

#define NR 100000L   // N rows
#define KC 96        // split-K chunks for utx
#define CHN 1088L    // n-chunk per utx block = 17*64
#define LSTR 72      // padded LDS row stride (elements) for [*][64] bf16 tiles

typedef __attribute__((ext_vector_type(8))) short s16x8;
typedef __attribute__((ext_vector_type(4))) short s16x4;
typedef __attribute__((ext_vector_type(4))) float f32x4;

__device__ __forceinline__ unsigned short f2bf(float f) {
  union { float f; unsigned u; } v; v.f = f;
  unsigned r = v.u + 0x7FFFu + ((v.u >> 16) & 1u);   // RNE
  return (unsigned short)(r >> 16);
}
__device__ __forceinline__ float bf2f(unsigned short s) {
  union { unsigned u; float f; } v; v.u = ((unsigned)s) << 16;
  return v.f;
}
__device__ __forceinline__ f32x4 MF(s16x8 a, s16x8 b, f32x4 c) {
  return __builtin_amdgcn_mfma_f32_16x16x32_bf16(a, b, c, 0, 0, 0);
}

// ---------- LDS staging: tiles [ROWS][64] bf16 at padded stride LSTR=72 ----------
template<int ROWS>
__device__ __forceinline__ void stage_rows(unsigned short* lds, const unsigned short* src,
    long pitch, long r0, long rlim, long k0, long klim, int tid) {
  const int f8 = tid & 7;
#pragma unroll
  for (int it = 0; it < ROWS / 32; ++it) {
    const int row = (tid >> 3) + it * 32;
    const long gr = r0 + row;
    const long gk = k0 + f8 * 8;
    s16x8 v = {};
    if (gr < rlim && gk < klim)
      v = *(const s16x8*)(src + gr * pitch + gk);
    *(s16x8*)(lds + row * LSTR + f8 * 8) = v;
  }
}

template<int ROWS>
__device__ __forceinline__ void stage_rows_f32(unsigned short* lds, const float* src,
    long pitch, long r0, long rlim, long k0, long klim, int tid) {
  const int f4 = tid & 15;
#pragma unroll
  for (int it = 0; it < ROWS / 16; ++it) {
    const int row = (tid >> 4) + it * 16;
    const long gr = r0 + row;
    const long gk = k0 + f4 * 4;
    f32x4 v = {};
    if (gr < rlim && gk < klim)
      v = *(const f32x4*)(src + gr * pitch + gk);
    s16x4 o;
    o[0] = (short)f2bf(v[0]); o[1] = (short)f2bf(v[1]);
    o[2] = (short)f2bf(v[2]); o[3] = (short)f2bf(v[3]);
    *(s16x4*)(lds + row * LSTR + f4 * 4) = o;
  }
}

// T0-fallback transposed stager (scalar; 8-way conflicts — only used if ws too small)
__device__ __forceinline__ void stage_utr_f32(unsigned short* lds, const float* u,
    long n0, long m0, int tid) {
  const int mm = tid & 63;
  const int base = tid >> 6;
#pragma unroll
  for (int it = 0; it < 16; ++it) {
    const int nl = base + it * 4;
    const long n = n0 + nl;
    unsigned short v = 0;
    if (n < NR) v = f2bf(u[n * 512 + m0 + mm]);
    lds[mm * LSTR + nl] = v;
  }
}

// Fragment reader: lane l holds row (passed), k = kk*32 + (l>>4)*8 .. +8 contiguous.
__device__ __forceinline__ s16x8 fragA(const unsigned short* lds, int row, int kk, int lane) {
  return *(const s16x8*)(lds + row * LSTR + kk * 32 + ((lane >> 4) << 3));
}

// ---------- prep ----------
__global__ void k_prep(const float* __restrict__ e0, const float* __restrict__ e1,
    const float* __restrict__ fe_w1, const float* __restrict__ fe_w2,
    const float* __restrict__ eig_w, const float* __restrict__ eig_b,
    const float* __restrict__ lw, const float* __restrict__ fW,
    unsigned short* __restrict__ W1T, unsigned short* __restrict__ W2T,
    float* __restrict__ eig, float* __restrict__ coef) {
  long id = (long)blockIdx.x * 256 + threadIdx.x;
  if (id < 65536) {                       // W1T[j][k]
    int j = (int)(id >> 9), k = (int)(id & 511);
    W1T[id] = (k < 500) ? f2bf(fe_w1[(long)k * 128 + j]) : (unsigned short)0;
  } else if (id < 65536 + 16384) {        // W2T[j][k]
    long q = id - 65536; int j = (int)(q >> 7), k = (int)(q & 127);
    W2T[q] = f2bf(fe_w2[(long)k * 128 + j]);
  } else if (id < 65536 + 16384 + 1024) { // eig[b][m]
    long q = id - 65536 - 16384; int b = (int)(q >> 9), m = (int)(q & 511);
    const float* e = b ? e1 : e0;
    float s = eig_b[0] + eig_w[0];
    float pe = 3.14159265358979323846f * e[m];
    for (int f = 1; f <= 128; ++f) s += cosf(pe * (float)f) * eig_w[f];
    eig[q] = s;
  } else if (id < 65536 + 16384 + 1024 + 256) { // coef[L][{c0,c1}][j]
    long q = id - 65536 - 16384 - 1024; int L = (int)(q >> 7), j = (int)(q & 127);
    float tail = 0.f;
    for (int k = 1; k <= 10; ++k) tail += fW[k];
    float w0 = lw[L * 256 + j], w1 = lw[L * 256 + 128 + j];
    coef[L * 256 + j] = w0 + fW[0] * w1;
    coef[L * 256 + 128 + j] = tail * w1;
  }
}

// ---------- convert+transpose u: Ubf[n][m] (optional) and UbT[m][n], both bf16 ----------
template<int WRITE_UB>
__global__ __launch_bounds__(256) void k_cvtT(const float* __restrict__ u,
    unsigned short* __restrict__ Ubf, unsigned short* __restrict__ UbT) {
  __shared__ float T[64][65];
  const int tid = threadIdx.x;
  const int nt = blockIdx.x >> 3;        // n-tile
  const int mt = blockIdx.x & 7;         // m-tile
  const long n0 = (long)nt * 64, m0 = (long)mt * 64;
  const int c4 = (tid & 15) * 4;
#pragma unroll
  for (int p = 0; p < 4; ++p) {
    const int rr = (tid >> 4) + p * 16;
    const long n = n0 + rr;
    f32x4 v = {};
    if (n < NR) v = *(const f32x4*)(u + n * 512 + m0 + c4);
    T[rr][c4 + 0] = v[0]; T[rr][c4 + 1] = v[1];
    T[rr][c4 + 2] = v[2]; T[rr][c4 + 3] = v[3];
    if (WRITE_UB && n < NR) {
      s16x4 o;
      o[0] = (short)f2bf(v[0]); o[1] = (short)f2bf(v[1]);
      o[2] = (short)f2bf(v[2]); o[3] = (short)f2bf(v[3]);
      *(s16x4*)(Ubf + n * 512 + m0 + c4) = o;
    }
  }
  __syncthreads();
  // UbT[m0+mm][n0+c4 .. +3]; quarter-wave lanes share mm, write consecutive n (coalesced)
#pragma unroll
  for (int p = 0; p < 4; ++p) {
    const int mm = (tid >> 4) + p * 16;
    s16x4 o;
#pragma unroll
    for (int e = 0; e < 4; ++e) o[e] = (short)f2bf(T[c4 + e][mm]);
    const long nbase = n0 + c4;
    if (nbase + 3 < NR) {
      *(s16x4*)(UbT + (long)(m0 + mm) * NR + nbase) = o;
    } else {
#pragma unroll
      for (int e = 0; e < 4; ++e)
        if (nbase + e < NR) UbT[(long)(m0 + mm) * NR + nbase + e] = o[e];
    }
  }
}

// ---------- GEMM1: t[n][j] = relu(x @ W1 + b1) ----------
__global__ __launch_bounds__(256) void k_gemm1(const float* __restrict__ x,
    const unsigned short* __restrict__ W1T, const float* __restrict__ b1,
    unsigned short* __restrict__ t) {
  __shared__ __align__(16) unsigned short Al[64 * LSTR];
  __shared__ __align__(16) unsigned short Bl[128 * LSTR];
  const int tid = threadIdx.x, lane = tid & 63, w = tid >> 6;
  const long n0 = (long)blockIdx.x * 64;
  f32x4 acc[8] = {};
  for (int kt = 0; kt < 8; ++kt) {
    stage_rows_f32<64>(Al, x, 500, n0, NR, kt * 64L, 500, tid);
    stage_rows<128>(Bl, W1T, 512, 0, 1L << 40, kt * 64L, 512, tid);
    __syncthreads();
#pragma unroll
    for (int kk = 0; kk < 2; ++kk) {
      s16x8 af = fragA(Al, (w << 4) + (lane & 15), kk, lane);
#pragma unroll
      for (int ct = 0; ct < 8; ++ct) {
        s16x8 bfr = fragA(Bl, (ct << 4) + (lane & 15), kk, lane);
        acc[ct] = MF(af, bfr, acc[ct]);
      }
    }
    __syncthreads();
  }
  const int cl = lane & 15, g = lane >> 4;
#pragma unroll
  for (int ct = 0; ct < 8; ++ct) {
    int j = (ct << 4) + cl;
    float bias = b1[j];
#pragma unroll
    for (int r = 0; r < 4; ++r) {
      long n = n0 + (w << 4) + (g << 2) + r;
      if (n < NR) {
        float v = acc[ct][r] + bias;
        t[n * 128 + j] = f2bf(v > 0.f ? v : 0.f);
      }
    }
  }
}

// ---------- GEMM2: hT[j][n] = (t @ W2 + b2)^T ----------
__global__ __launch_bounds__(256) void k_gemm2(const unsigned short* __restrict__ W2T,
    const unsigned short* __restrict__ t, const float* __restrict__ b2,
    unsigned short* __restrict__ hT) {
  __shared__ __align__(16) unsigned short Al[128 * LSTR];
  __shared__ __align__(16) unsigned short Bl[64 * LSTR];
  const int tid = threadIdx.x, lane = tid & 63, w = tid >> 6;
  const long n0 = (long)blockIdx.x * 64;
  f32x4 acc[8] = {};
  for (int kt = 0; kt < 2; ++kt) {
    stage_rows<128>(Al, W2T, 128, 0, 1L << 40, kt * 64L, 128, tid);
    stage_rows<64>(Bl, t, 128, n0, NR, kt * 64L, 128, tid);
    __syncthreads();
#pragma unroll
    for (int kk = 0; kk < 2; ++kk) {
      s16x8 bfr = fragA(Bl, (w << 4) + (lane & 15), kk, lane);
#pragma unroll
      for (int rt = 0; rt < 8; ++rt) {
        s16x8 af = fragA(Al, (rt << 4) + (lane & 15), kk, lane);
        acc[rt] = MF(af, bfr, acc[rt]);
      }
    }
    __syncthreads();
  }
  const int cl = lane & 15, g = lane >> 4;
  long n = n0 + (w << 4) + cl;
  if (n < NR) {
#pragma unroll
    for (int rt = 0; rt < 8; ++rt)
#pragma unroll
      for (int r = 0; r < 4; ++r) {
        int j = (rt << 4) + (g << 2) + r;
        hT[(long)j * NR + n] = f2bf(acc[rt][r] + b2[j]);
      }
  }
}

// ---------- utx (split-K, MFMA, vector-staged): P[c][j][m] += hT·u over n-chunk ----------
__global__ __launch_bounds__(256) void k_utx(const unsigned short* __restrict__ hT,
    const unsigned short* __restrict__ UbT, float* __restrict__ P) {
  __shared__ __align__(16) unsigned short Al[128 * LSTR];
  __shared__ __align__(16) unsigned short Bl[64 * LSTR];
  const int tid = threadIdx.x, lane = tid & 63, w = tid >> 6;
  const int mt = blockIdx.x & 7, c = blockIdx.x >> 3;
  const long m0 = (long)mt * 64, nb = (long)c * CHN;
  f32x4 acc[8] = {};
  for (int kt = 0; kt < 17; ++kt) {
    const long n0 = nb + kt * 64;
    stage_rows<128>(Al, hT, NR, 0, 1L << 40, n0, NR, tid);
    stage_rows<64>(Bl, UbT, NR, m0, 512, n0, NR, tid);
    __syncthreads();
#pragma unroll
    for (int kk = 0; kk < 2; ++kk) {
      s16x8 bfr = fragA(Bl, (w << 4) + (lane & 15), kk, lane);
#pragma unroll
      for (int rt = 0; rt < 8; ++rt) {
        s16x8 af = fragA(Al, (rt << 4) + (lane & 15), kk, lane);
        acc[rt] = MF(af, bfr, acc[rt]);
      }
    }
    __syncthreads();
  }
  const int cl = lane & 15, g = lane >> 4;
  const long m = m0 + (w << 4) + cl;
  float* Pc = P + (long)c * 65536;
#pragma unroll
  for (int rt = 0; rt < 8; ++rt)
#pragma unroll
    for (int r = 0; r < 4; ++r) {
      int j = (rt << 4) + (g << 2) + r;
      Pc[(long)j * 512 + m] = acc[rt][r];
    }
}

// T0 fallback: scalar-transpose utx (reads u f32 directly)
__global__ __launch_bounds__(256) void k_utx0(const unsigned short* __restrict__ hT,
    const float* __restrict__ u, float* __restrict__ P) {
  __shared__ __align__(16) unsigned short Al[128 * LSTR];
  __shared__ __align__(16) unsigned short Bl[64 * LSTR];
  const int tid = threadIdx.x, lane = tid & 63, w = tid >> 6;
  const int mt = blockIdx.x & 7, c = blockIdx.x >> 3;
  const long m0 = (long)mt * 64, nb = (long)c * CHN;
  f32x4 acc[8] = {};
  for (int kt = 0; kt < 17; ++kt) {
    const long n0 = nb + kt * 64;
    stage_rows<128>(Al, hT, NR, 0, 1L << 40, n0, NR, tid);
    stage_utr_f32(Bl, u, n0, m0, tid);
    __syncthreads();
#pragma unroll
    for (int kk = 0; kk < 2; ++kk) {
      s16x8 bfr = fragA(Bl, (w << 4) + (lane & 15), kk, lane);
#pragma unroll
      for (int rt = 0; rt < 8; ++rt) {
        s16x8 af = fragA(Al, (rt << 4) + (lane & 15), kk, lane);
        acc[rt] = MF(af, bfr, acc[rt]);
      }
    }
    __syncthreads();
  }
  const int cl = lane & 15, g = lane >> 4;
  const long m = m0 + (w << 4) + cl;
  float* Pc = P + (long)c * 65536;
#pragma unroll
  for (int rt = 0; rt < 8; ++rt)
#pragma unroll
    for (int r = 0; r < 4; ++r) {
      int j = (rt << 4) + (g << 2) + r;
      Pc[(long)j * 512 + m] = acc[rt][r];
    }
}

// ---------- reduce split-K partials, apply eig scaling -> sT[j][m] bf16 ----------
__global__ void k_reduce(const float* __restrict__ P, const float* __restrict__ eig,
                         unsigned short* __restrict__ sT) {
  const int idx = blockIdx.x * 256 + threadIdx.x;   // 65536
  const int m = idx & 511;
  float s = 0.f;
#pragma unroll 4
  for (int c = 0; c < KC; ++c) s += P[(long)c * 65536 + idx];
  sT[idx] = f2bf(s * eig[m]);
}

// ---------- r-GEMM (MFMA) + fused layer update/LN/ReLU ----------
template<int UBF>
__global__ __launch_bounds__(256) void k_rgemm(const unsigned short* __restrict__ sT,
    const void* __restrict__ uraw, const unsigned short* __restrict__ hin,
    unsigned short* __restrict__ hout, const float* __restrict__ c0,
    const float* __restrict__ c1, const float* __restrict__ gam,
    const float* __restrict__ bet) {
  __shared__ __align__(16) unsigned short Al[128 * LSTR];
  __shared__ __align__(16) unsigned short Bl[64 * LSTR];
  const int tid = threadIdx.x, lane = tid & 63, w = tid >> 6;
  const long n0 = (long)blockIdx.x * 64;
  f32x4 acc[8] = {};
  for (int kt = 0; kt < 8; ++kt) {
    stage_rows<128>(Al, sT, 512, 0, 1L << 40, kt * 64L, 512, tid);
    if (UBF) stage_rows<64>(Bl, (const unsigned short*)uraw, 512, n0, NR, kt * 64L, 512, tid);
    else     stage_rows_f32<64>(Bl, (const float*)uraw, 512, n0, NR, kt * 64L, 512, tid);
    __syncthreads();
#pragma unroll
    for (int kk = 0; kk < 2; ++kk) {
      s16x8 bfr = fragA(Bl, (w << 4) + (lane & 15), kk, lane);
#pragma unroll
      for (int rt = 0; rt < 8; ++rt) {
        s16x8 af = fragA(Al, (rt << 4) + (lane & 15), kk, lane);
        acc[rt] = MF(af, bfr, acc[rt]);
      }
    }
    __syncthreads();
  }
  const int cl = lane & 15, g = lane >> 4;
  const long n = n0 + (w << 4) + cl;
  const bool valid = n < NR;
  float pre[8][4];
  float sum = 0.f, ssq = 0.f;
#pragma unroll
  for (int rt = 0; rt < 8; ++rt)
#pragma unroll
    for (int r = 0; r < 4; ++r) {
      int j = (rt << 4) + (g << 2) + r;
      float hp = valid ? bf2f(hin[(long)j * NR + n]) : 0.f;
      float pv = hp * c0[j] + c1[j] * acc[rt][r];
      pre[rt][r] = pv;
      sum += pv; ssq += pv * pv;
    }
  sum += __shfl_xor(sum, 16, 64); sum += __shfl_xor(sum, 32, 64);
  ssq += __shfl_xor(ssq, 16, 64); ssq += __shfl_xor(ssq, 32, 64);
  const float mu = sum * (1.f / 128.f);
  const float var = ssq * (1.f / 128.f) - mu * mu;
  const float rs = rsqrtf(var + 1e-5f);
  if (valid) {
#pragma unroll
    for (int rt = 0; rt < 8; ++rt)
#pragma unroll
      for (int r = 0; r < 4; ++r) {
        int j = (rt << 4) + (g << 2) + r;
        float o = (pre[rt][r] - mu) * rs * gam[j] + bet[j];
        hout[(long)j * NR + n] = f2bf(o > 0.f ? o : 0.f);
      }
  }
}

// ---------- final: attention mix + 128->40 GEMV + log_softmax ----------
__global__ __launch_bounds__(256) void k_final(const unsigned short* __restrict__ R0,
    const unsigned short* __restrict__ R1, const unsigned short* __restrict__ R2,
    const float* __restrict__ att0, const float* __restrict__ att1,
    const float* __restrict__ att2, const float* __restrict__ av,
    const float* __restrict__ W, const float* __restrict__ bias,
    float* __restrict__ out) {
  __shared__ __align__(16) float Wl[128 * 40];
  __shared__ float Av[3][128];
  __shared__ float zb[256 * 41];
  const int tid = threadIdx.x;
  for (int i = tid; i < 5120; i += 256) Wl[i] = W[i];
  if (tid < 128) { Av[0][tid] = att0[tid]; Av[1][tid] = att1[tid]; Av[2][tid] = att2[tid]; }
  __syncthreads();
  const long n0 = (long)blockIdx.x * 256;
  const long n = n0 + tid;
  const long nn = n < NR ? n : NR - 1;
  float a0 = 0.f, a1 = 0.f, a2 = 0.f;
  for (int j = 0; j < 128; ++j) {
    a0 += bf2f(R0[(long)j * NR + nn]) * Av[0][j];
    a1 += bf2f(R1[(long)j * NR + nn]) * Av[1][j];
    a2 += bf2f(R2[(long)j * NR + nn]) * Av[2][j];
  }
  const float s0 = 1.f / (1.f + expf(-a0));
  const float s1 = 1.f / (1.f + expf(-a1));
  const float s2 = 1.f / (1.f + expf(-a2));
  const float l0 = s0 * av[0] + s1 * av[3] + s2 * av[6];
  const float l1 = s0 * av[1] + s1 * av[4] + s2 * av[7];
  const float l2 = s0 * av[2] + s1 * av[5] + s2 * av[8];
  const float mx = fmaxf(l0, fmaxf(l1, l2));
  const float e0v = expf(l0 - mx), e1v = expf(l1 - mx), e2v = expf(l2 - mx);
  const float inv = 1.f / (e0v + e1v + e2v);
  const float w0 = e0v * inv, w1 = e1v * inv, w2 = e2v * inv;
  float z[40];
#pragma unroll
  for (int c = 0; c < 40; ++c) z[c] = bias[c];
  for (int j = 0; j < 128; ++j) {
    const float h = w0 * bf2f(R0[(long)j * NR + nn]) + w1 * bf2f(R1[(long)j * NR + nn])
                  + w2 * bf2f(R2[(long)j * NR + nn]);
#pragma unroll
    for (int c4 = 0; c4 < 10; ++c4) {
      f32x4 wv = *(const f32x4*)(&Wl[j * 40 + c4 * 4]);
      z[c4 * 4 + 0] += h * wv[0];
      z[c4 * 4 + 1] += h * wv[1];
      z[c4 * 4 + 2] += h * wv[2];
      z[c4 * 4 + 3] += h * wv[3];
    }
  }
  float mz = z[0];
#pragma unroll
  for (int c = 1; c < 40; ++c) mz = fmaxf(mz, z[c]);
  float se = 0.f;
#pragma unroll
  for (int c = 0; c < 40; ++c) se += expf(z[c] - mz);
  const float ls = logf(se);
#pragma unroll
  for (int c = 0; c < 40; ++c) zb[tid * 41 + c] = z[c] - mz - ls;
  __syncthreads();
  long rows = NR - n0; if (rows > 256) rows = 256;
  const long cnt = rows * 40;
  for (long i = tid; i < cnt; i += 256)
    out[n0 * 40 + i] = zb[(i / 40) * 41 + (i % 40)];
}

extern "C" void kernel_launch(void* const* d_in, const int* in_sizes, int n_in,
                              void* d_out, int out_size, void* d_ws, size_t ws_size,
                              hipStream_t stream) {
  const float* x      = (const float*)d_in[0];
  const float* e0     = (const float*)d_in[1];
  const float* e1     = (const float*)d_in[2];
  const float* u0     = (const float*)d_in[3];
  const float* u1     = (const float*)d_in[4];
  const float* fe_w1  = (const float*)d_in[5];
  const float* fe_b1  = (const float*)d_in[6];
  const float* fe_w2  = (const float*)d_in[7];
  const float* fe_b2  = (const float*)d_in[8];
  const float* eig_w  = (const float*)d_in[9];
  const float* eig_bi = (const float*)d_in[10];
  const float* lw     = (const float*)d_in[11];
  const float* ln_g   = (const float*)d_in[12];
  const float* ln_b   = (const float*)d_in[13];
  const float* fW     = (const float*)d_in[14];
  const float* att0   = (const float*)d_in[15];
  const float* att1   = (const float*)d_in[16];
  const float* att2   = (const float*)d_in[17];
  const float* attv   = (const float*)d_in[18];
  const float* lin3w  = (const float*)d_in[19];
  const float* lin3b  = (const float*)d_in[20];
  float* out = (float*)d_out;

  const size_t SZ_H = (size_t)NR * 128 * 2;        // 25,600,000
  const size_t SZ_P = (size_t)KC * 65536 * 4;      // 25,165,824
  const size_t SZ_U = (size_t)NR * 512 * 2;        // 102,400,000

  char* p = (char*)d_ws;
  unsigned short* R0T = (unsigned short*)p; p += SZ_H;
  unsigned short* R1T = (unsigned short*)p; p += SZ_H;
  unsigned short* R2T = (unsigned short*)p; p += SZ_H;
  float* P            = (float*)p;          p += SZ_P;
  unsigned short* W1T = (unsigned short*)p; p += 131072;
  unsigned short* W2T = (unsigned short*)p; p += 32768;
  unsigned short* sT  = (unsigned short*)p; p += 131072;
  float* eig          = (float*)p;          p += 4096;
  float* coef         = (float*)p;          p += 2048;
  const size_t base = (size_t)(p - (char*)d_ws);
  const int tier = (ws_size >= base + 2 * SZ_U) ? 2 : (ws_size >= base + SZ_U) ? 1 : 0;
  unsigned short* UbT = nullptr;
  unsigned short* Ubf = nullptr;
  if (tier >= 1) { UbT = (unsigned short*)p; p += SZ_U; }
  if (tier >= 2) { Ubf = (unsigned short*)p; p += SZ_U; }

  k_prep<<<325, 256, 0, stream>>>(e0, e1, fe_w1, fe_w2, eig_w, eig_bi, lw, fW,
                                  W1T, W2T, eig, coef);
  const int GB = (int)((NR + 63) / 64);   // 1563
  // t scratch -> R1T (dead until branch-0 L0 output)
  k_gemm1<<<GB, 256, 0, stream>>>(x, W1T, fe_b1, R1T);
  k_gemm2<<<GB, 256, 0, stream>>>(W2T, R1T, fe_b2, R0T);

  for (int b = 0; b < 2; ++b) {
    const float* u = b ? u1 : u0;
    if (tier == 2)      k_cvtT<1><<<GB * 8, 256, 0, stream>>>(u, Ubf, UbT);
    else if (tier == 1) k_cvtT<0><<<GB * 8, 256, 0, stream>>>(u, nullptr, UbT);
    // h carries across branches: branch 1 starts from branch 0's final h (R1T).
    const unsigned short* hin = (b == 0) ? R0T : R1T;
    unsigned short* hb = b ? R2T : R1T;   // L0 out; L1 runs in-place on hb
    for (int L = 0; L < 2; ++L) {
      unsigned short* hout = hb;
      if (tier >= 1) k_utx<<<8 * KC, 256, 0, stream>>>(hin, UbT, P);
      else           k_utx0<<<8 * KC, 256, 0, stream>>>(hin, u, P);
      k_reduce<<<256, 256, 0, stream>>>(P, eig + b * 512, sT);
      if (tier == 2)
        k_rgemm<1><<<GB, 256, 0, stream>>>(sT, (const void*)Ubf, hin, hout,
            coef + L * 256, coef + L * 256 + 128, ln_g + L * 128, ln_b + L * 128);
      else
        k_rgemm<0><<<GB, 256, 0, stream>>>(sT, (const void*)u, hin, hout,
            coef + L * 256, coef + L * 256 + 128, ln_g + L * 128, ln_b + L * 128);
      hin = hout;
    }
  }
  k_final<<<(int)((NR + 255) / 256), 256, 0, stream>>>(R0T, R1T, R2T,
      att0, att1, att2, attv, lin3w, lin3b, out);
}